// Round 6
// baseline (202.171 us; speedup 1.0000x reference)
//
#include <hip/hip_runtime.h>
#include <math.h>

// Elastic transform: [32,256,1024,3] fp32, 3x3 control grid displacement.
//   k_disp    : dense dy/dx fields [256,1024] from 3x3 control points
//   k_prefilt : FUSED W+H cubic-spline prefilter (17-tap mirror FIR each),
//               x -> planar coefP [b][c][h][w]; tile 64h x 32w + 8-halo in LDS
//   k_sample  : 4x4 cubic gather, 4 batches per thread (weights amortized),
//               planar taps, LDS-staged coalesced output

#define H_ 256
#define W_ 1024
#define B_ 32
#define RAD 8                // |z|^9 trunc err ~1e-4 << 2e-2 threshold
#define ROWF 3072            // W_*3 floats per (b,h) row of x
#define HW_ (H_ * W_)        // 262144 floats per plane
#define SROW 145             // LDS row stride (odd -> bank-rotating columns)
#define NSEG 36              // 36 float4 = 144 floats = 48 cols * 3ch per row

typedef float f4a __attribute__((ext_vector_type(4), aligned(4)));

__device__ __forceinline__ float b3f(float t) {
    float a = fabsf(t);
    if (a < 1.0f) return (4.0f - 6.0f * a * a + 3.0f * a * a * a) * (1.0f / 6.0f);
    if (a < 2.0f) { float s = 2.0f - a; return s * s * s * (1.0f / 6.0f); }
    return 0.0f;
}

__device__ __forceinline__ void cubw(float f, float* w) {
    float f2 = f * f, f3 = f2 * f;
    float om = 1.0f - f;
    w[0] = om * om * om * (1.0f / 6.0f);
    w[1] = (3.0f * f3 - 6.0f * f2 + 4.0f) * (1.0f / 6.0f);
    w[2] = (-3.0f * f3 + 3.0f * f2 + 3.0f * f + 1.0f) * (1.0f / 6.0f);
    w[3] = f3 * (1.0f / 6.0f);
}

__device__ __forceinline__ float clamp01(float v) {
    return fminf(fmaxf(v, 0.0f), 1.0f);
}

__device__ __forceinline__ void basis3(int i, int n, float& w0, float& w1, float& w2) {
    float u = (float)i * 2.0f / (float)(n - 1);
    int base = (int)floorf(u);
    w0 = w1 = w2 = 0.0f;
#pragma unroll
    for (int k = -1; k < 3; ++k) {
        int id = base + k;
        float bw = b3f(u - (float)id);
        int j = id < 0 ? -id : id;
        j &= 3;
        if (j == 3) j = 1;
        if (j == 0) w0 += bw; else if (j == 1) w1 += bw; else w2 += bw;
    }
}

// ---------------- kernel 0: displacement fields ----------------
__global__ __launch_bounds__(256) void k_disp(const float* __restrict__ disp,
                                              float* __restrict__ dyp,
                                              float* __restrict__ dxp) {
    int idx = blockIdx.x * 256 + threadIdx.x;
    int h = idx >> 10, w = idx & 1023;

    const float A[3][3] = {{1.75f, -1.0f, 0.25f},
                           {-0.5f,  2.0f, -0.5f},
                           {0.25f, -1.0f, 1.75f}};
    float Ty[3][3], Tx[3][3];
#pragma unroll
    for (int i = 0; i < 3; ++i)
#pragma unroll
        for (int j = 0; j < 3; ++j) {
            float ty = 0.f, tx = 0.f;
#pragma unroll
            for (int k = 0; k < 3; ++k) {
                ty += A[i][k] * (5.0f * disp[k * 3 + j]);
                tx += A[i][k] * (5.0f * disp[9 + k * 3 + j]);
            }
            Ty[i][j] = ty; Tx[i][j] = tx;
        }
    float Cy[3][3], Cx[3][3];
#pragma unroll
    for (int i = 0; i < 3; ++i)
#pragma unroll
        for (int j = 0; j < 3; ++j) {
            float ty = 0.f, tx = 0.f;
#pragma unroll
            for (int k = 0; k < 3; ++k) {
                ty += Ty[i][k] * A[j][k];
                tx += Tx[i][k] * A[j][k];
            }
            Cy[i][j] = ty; Cx[i][j] = tx;
        }

    float rh0, rh1, rh2, rw0, rw1, rw2;
    basis3(h, H_, rh0, rh1, rh2);
    basis3(w, W_, rw0, rw1, rw2);
    float rh[3] = {rh0, rh1, rh2}, rw[3] = {rw0, rw1, rw2};

    float dy = 0.f, dx = 0.f;
#pragma unroll
    for (int i = 0; i < 3; ++i)
#pragma unroll
        for (int j = 0; j < 3; ++j) {
            dy += rh[i] * Cy[i][j] * rw[j];
            dx += rh[i] * Cx[i][j] * rw[j];
        }
    dyp[idx] = dy;
    dxp[idx] = dx;
}

// ---------------- kernel 1: fused W+H prefilter ----------------
// grid (32, 4, 32) = (w-chunk of 32, h-chunk of 64, batch), 192 threads.
// LDS [80 rows][145 floats]: rows h0-8..h0+71, cols (w0-8..w0+39)x3ch.
// Mirror halos resolved by internal LDS copies (always map inside the tile).
__global__ __launch_bounds__(192) void k_prefilt(const float* __restrict__ x,
                                                 float* __restrict__ coefP) {
    __shared__ float L[80 * SROW];     // 46.4 KiB
    const int t = threadIdx.x;
    const int w0 = blockIdx.x * 32;
    const int h0 = blockIdx.y * 64;
    const int b = blockIdx.z;

    // ---- stage full 80 x 36-float4 grid (edge slots garbage, fixed below) --
    const float* xb = x + (size_t)b * (H_ * ROWF);
    const int fbase = (w0 - 8) * 3;
#pragma unroll 1
    for (int i = t; i < 80 * NSEG; i += 192) {
        int r = i / NSEG, s = i - r * NSEG;
        int hg = min(max(h0 - 8 + r, 0), H_ - 1);
        int ofs = min(max(fbase + 4 * s, 0), ROWF - 4);
        float4 v = *(const float4*)(xb + (size_t)hg * ROWF + ofs);
        float* d = L + r * SROW + 4 * s;
        d[0] = v.x; d[1] = v.y; d[2] = v.z; d[3] = v.w;   // b32 (odd stride)
    }
    __syncthreads();

    // ---- mirror-fix rows (r invalid exactly where staging clamped) ----
    if (h0 == 0) {
        for (int i = t; i < 8 * SROW; i += 192) {
            int r = i / SROW, f = i - r * SROW;           // r = 0..7
            L[r * SROW + f] = L[(16 - r) * SROW + f];
        }
    } else if (h0 == 192) {
        for (int i = t; i < 8 * SROW; i += 192) {
            int r = 72 + i / SROW, f = i % SROW;          // r = 72..79
            L[r * SROW + f] = L[(142 - r) * SROW + f];
        }
    }
    __syncthreads();
    // ---- mirror-fix cols ----
    if (w0 == 0) {
        for (int i = t; i < 80 * 24; i += 192) {
            int r = i / 24, j = i - r * 24;
            int q = j / 3, cc = j - 3 * (j / 3);          // q = 0..7
            L[r * SROW + 3 * q + cc] = L[r * SROW + 3 * (16 - q) + cc];
        }
    } else if (w0 == 992) {
        for (int i = t; i < 80 * 24; i += 192) {
            int r = i / 24, j = i - r * 24;
            int q = 40 + j / 3, cc = j % 3;               // q = 40..47
            L[r * SROW + 3 * q + cc] = L[r * SROW + 3 * (78 - q) + cc];
        }
    }
    __syncthreads();

    float g[RAD + 1];
    g[0] = 1.7320508075688773f;
#pragma unroll
    for (int k = 1; k <= RAD; ++k) g[k] = g[k - 1] * (-0.26794919243112270647f);

    // ---- W-FIR in place: 240 row-tasks (3ch x 80 rows), row-private ----
#pragma unroll 1
    for (int task = t; task < 240; task += 192) {
        int c = task / 80, r = task - 80 * (task / 80);
        float in[48];
#pragma unroll
        for (int q = 0; q < 48; ++q) in[q] = L[r * SROW + 3 * q + c];
        float o[32];
#pragma unroll
        for (int i = 0; i < 32; ++i) {
            float a = g[0] * in[i + 8];
#pragma unroll
            for (int k = 1; k <= 8; ++k)
                a += g[k] * (in[i + 8 - k] + in[i + 8 + k]);
            o[i] = a;
        }
#pragma unroll
        for (int i = 0; i < 32; ++i) L[r * SROW + 3 * (8 + i) + c] = o[i];
    }
    __syncthreads();

    // ---- H-FIR -> global: 192 tasks = 3ch x 32w x 2 row-segments ----
    {
        const int c = t / 64, r6 = t & 63, seg = r6 >> 5, jo = r6 & 31;
        const int col = 3 * (8 + jo) + c;
        float v[48];
#pragma unroll
        for (int k = 0; k < 48; ++k) v[k] = L[(32 * seg + k) * SROW + col];
        float* dst = coefP + (size_t)(b * 3 + c) * HW_
                   + (size_t)(h0 + 32 * seg) * W_ + (w0 + jo);
#pragma unroll
        for (int i = 0; i < 32; ++i) {
            float a = g[0] * v[i + 8];
#pragma unroll
            for (int k = 1; k <= 8; ++k)
                a += g[k] * (v[i + 8 - k] + v[i + 8 + k]);
            dst[(size_t)i * W_] = a;
        }
    }
}

// ---------------- kernel 2: 4x4 cubic gather, 4 batches/thread ------------
// grid (1024, 8): thread owns (h,w) for batches b0..b0+3; setup amortized.
__global__ __launch_bounds__(256) void k_sample(const float* __restrict__ coefP,
                                                const float* __restrict__ dyp,
                                                const float* __restrict__ dxp,
                                                float* __restrict__ out) {
    __shared__ float os[768];
    const int t = threadIdx.x;
    const int hw = blockIdx.x * 256 + t;
    const int b0 = blockIdx.y * 4;
    const int h = hw >> 10, w = hw & 1023;

    float cy = (float)h + dyp[hw];
    float cx = (float)w + dxp[hw];
    float byf = floorf(cy), bxf = floorf(cx);
    int by = (int)byf, bx = (int)bxf;
    float wy[4], wx[4];
    cubw(cy - byf, wy);
    cubw(cx - bxf, wx);

    int iyW[4];
#pragma unroll
    for (int r = 0; r < 4; ++r)
        iyW[r] = min(max(by - 1 + r, 0), H_ - 1) * W_;

    const bool xin = (bx >= 1) && (bx <= W_ - 3);
    int offr[4], ix4[4];
#pragma unroll
    for (int r = 0; r < 4; ++r) offr[r] = iyW[r] + bx - 1;
#pragma unroll
    for (int k = 0; k < 4; ++k) ix4[k] = min(max(bx - 1 + k, 0), W_ - 1);

    const float* cb = coefP + (size_t)(b0 * 3) * HW_;
    const size_t ostride = (size_t)HW_ * 3;

#pragma unroll 1
    for (int bp = 0; bp < 2; ++bp) {
        float a[2][3];
#pragma unroll
        for (int u = 0; u < 2; ++u) {
            const float* p = cb + (size_t)(2 * bp + u) * 3 * HW_;
            float s0 = 0.f, s1 = 0.f, s2 = 0.f;
            if (xin) {
#pragma unroll
                for (int r = 0; r < 4; ++r) {
                    f4a v0 = *(const f4a*)(p + offr[r]);
                    f4a v1 = *(const f4a*)(p + HW_ + offr[r]);
                    f4a v2 = *(const f4a*)(p + 2 * HW_ + offr[r]);
                    float wyr = wy[r];
                    s0 += wyr * (wx[0] * v0.x + wx[1] * v0.y + wx[2] * v0.z + wx[3] * v0.w);
                    s1 += wyr * (wx[0] * v1.x + wx[1] * v1.y + wx[2] * v1.z + wx[3] * v1.w);
                    s2 += wyr * (wx[0] * v2.x + wx[1] * v2.y + wx[2] * v2.z + wx[3] * v2.w);
                }
            } else {
#pragma unroll
                for (int r = 0; r < 4; ++r) {
                    float wyr = wy[r];
#pragma unroll
                    for (int k = 0; k < 4; ++k) {
                        float wk = wyr * wx[k];
                        s0 += wk * p[iyW[r] + ix4[k]];
                        s1 += wk * p[HW_ + iyW[r] + ix4[k]];
                        s2 += wk * p[2 * HW_ + iyW[r] + ix4[k]];
                    }
                }
            }
            a[u][0] = clamp01(s0); a[u][1] = clamp01(s1); a[u][2] = clamp01(s2);
        }
#pragma unroll
        for (int u = 0; u < 2; ++u) {
            os[3 * t + 0] = a[u][0];
            os[3 * t + 1] = a[u][1];
            os[3 * t + 2] = a[u][2];
            __syncthreads();
            if (t < 192) {
                float4 v = *(const float4*)(os + 4 * t);
                *(float4*)(out + (size_t)(b0 + 2 * bp + u) * ostride
                           + (size_t)blockIdx.x * 768 + 4 * t) = v;
            }
            __syncthreads();
        }
    }
}

extern "C" void kernel_launch(void* const* d_in, const int* in_sizes, int n_in,
                              void* d_out, int out_size, void* d_ws, size_t ws_size,
                              hipStream_t stream) {
    const float* x = (const float*)d_in[0];      // [32,256,1024,3]
    const float* disp = (const float*)d_in[1];   // [2,3,3]
    float* out = (float*)d_out;

    char* ws = (char*)d_ws;
    float* coefP = (float*)ws;                                 // 96 MiB planar
    float* dy = (float*)(ws + 100663296ull);                   // 1 MiB
    float* dx = (float*)(ws + 100663296ull + 1048576ull);      // 1 MiB

    k_disp<<<dim3((H_ * W_) / 256), dim3(256), 0, stream>>>(disp, dy, dx);

    k_prefilt<<<dim3(32, 4, 32), dim3(192), 0, stream>>>(x, coefP);

    k_sample<<<dim3((H_ * W_) / 256, 8), dim3(256), 0, stream>>>(coefP, dy, dx, out);
}

// Round 8
// 125.502 us; speedup vs baseline: 1.6109x; 1.6109x over previous
//
#include <hip/hip_runtime.h>
#include <hip/hip_fp16.h>
#include <math.h>

// Elastic transform: [32,256,1024,3] fp32, 3x3 control grid displacement.
//   k_disp   : dense (dy,dx) float2 field [256,1024] from 3x3 control points
//   k_wfilt  : spline prefilter along W (17-tap mirror FIR, f32 math), x ->
//              plane01 (half2 per pixel: c0,c1 STORAGE ONLY) + plane2 (f32 c2)
//   k_hfilt  : prefilter along H in place, f32 math on both planes
//              (plane01 unpacked to f32, repacked at store)
//   k_sample : 4x4 cubic gather, one thread per (b,h,w); taps are aligned
//              dwordx4 on both planes, all math f32; LDS-staged output
//
// fp16 surface is STORAGE ONLY (pack at store, unpack after load) — R7's
// packed-fp16 arithmetic is eliminated as the prime failure suspect.

#define H_ 256
#define W_ 1024
#define B_ 32
#define RAD 8                // |z|^9 trunc err ~1e-4 << 2e-2 threshold
#define ROWF 3072            // W_*3 floats per (b,h) row of x
#define HW_ (H_ * W_)        // 262144 pixels per plane

typedef float f4a __attribute__((ext_vector_type(4), aligned(4)));

__device__ __forceinline__ float b3f(float t) {
    float a = fabsf(t);
    if (a < 1.0f) return (4.0f - 6.0f * a * a + 3.0f * a * a * a) * (1.0f / 6.0f);
    if (a < 2.0f) { float s = 2.0f - a; return s * s * s * (1.0f / 6.0f); }
    return 0.0f;
}

__device__ __forceinline__ void cubw(float f, float* w) {
    float f2 = f * f, f3 = f2 * f;
    float om = 1.0f - f;
    w[0] = om * om * om * (1.0f / 6.0f);
    w[1] = (3.0f * f3 - 6.0f * f2 + 4.0f) * (1.0f / 6.0f);
    w[2] = (-3.0f * f3 + 3.0f * f2 + 3.0f * f + 1.0f) * (1.0f / 6.0f);
    w[3] = f3 * (1.0f / 6.0f);
}

__device__ __forceinline__ float clamp01(float v) {
    return fminf(fmaxf(v, 0.0f), 1.0f);
}

__device__ __forceinline__ float2 up2(float d) {        // half2 dword -> 2 f32
    return __half22float2(__builtin_bit_cast(__half2, d));
}
__device__ __forceinline__ float pk2(float a, float b) { // 2 f32 -> half2 dword
    return __builtin_bit_cast(float, __floats2half2_rn(a, b));
}

__device__ __forceinline__ void basis3(int i, int n, float& w0, float& w1, float& w2) {
    float u = (float)i * 2.0f / (float)(n - 1);
    int base = (int)floorf(u);
    w0 = w1 = w2 = 0.0f;
#pragma unroll
    for (int k = -1; k < 3; ++k) {
        int id = base + k;
        float bw = b3f(u - (float)id);
        int j = id < 0 ? -id : id;
        j &= 3;
        if (j == 3) j = 1;
        if (j == 0) w0 += bw; else if (j == 1) w1 += bw; else w2 += bw;
    }
}

// ---------------- kernel 0: displacement field (dy,dx) --------------------
__global__ __launch_bounds__(256) void k_disp(const float* __restrict__ disp,
                                              float2* __restrict__ dxy) {
    int idx = blockIdx.x * 256 + threadIdx.x;
    int h = idx >> 10, w = idx & 1023;

    const float A[3][3] = {{1.75f, -1.0f, 0.25f},
                           {-0.5f,  2.0f, -0.5f},
                           {0.25f, -1.0f, 1.75f}};
    float Ty[3][3], Tx[3][3];
#pragma unroll
    for (int i = 0; i < 3; ++i)
#pragma unroll
        for (int j = 0; j < 3; ++j) {
            float ty = 0.f, tx = 0.f;
#pragma unroll
            for (int k = 0; k < 3; ++k) {
                ty += A[i][k] * (5.0f * disp[k * 3 + j]);
                tx += A[i][k] * (5.0f * disp[9 + k * 3 + j]);
            }
            Ty[i][j] = ty; Tx[i][j] = tx;
        }
    float Cy[3][3], Cx[3][3];
#pragma unroll
    for (int i = 0; i < 3; ++i)
#pragma unroll
        for (int j = 0; j < 3; ++j) {
            float ty = 0.f, tx = 0.f;
#pragma unroll
            for (int k = 0; k < 3; ++k) {
                ty += Ty[i][k] * A[j][k];
                tx += Tx[i][k] * A[j][k];
            }
            Cy[i][j] = ty; Cx[i][j] = tx;
        }

    float rh0, rh1, rh2, rw0, rw1, rw2;
    basis3(h, H_, rh0, rh1, rh2);
    basis3(w, W_, rw0, rw1, rw2);
    float rh[3] = {rh0, rh1, rh2}, rw[3] = {rw0, rw1, rw2};

    float dy = 0.f, dx = 0.f;
#pragma unroll
    for (int i = 0; i < 3; ++i)
#pragma unroll
        for (int j = 0; j < 3; ++j) {
            dy += rh[i] * Cy[i][j] * rw[j];
            dx += rh[i] * Cx[i][j] * rw[j];
        }
    dxy[idx] = make_float2(dy, dx);
}

// ---------------- kernel 1: prefilter along W (f32 math) ------------------
// per channel LDS: [8 halo][1024][8 halo] = 1040, stride 1040
#define PLN 1040
__global__ __launch_bounds__(256) void k_wfilt(const float* __restrict__ x,
                                               float* __restrict__ p01,  // half2/pixel
                                               float* __restrict__ p2) { // f32/pixel
    __shared__ float pl[3 * PLN];        // 12480 B
    const int bp = blockIdx.x;           // b*256 + h
    const int t = threadIdx.x;
    const float* row = x + (size_t)bp * ROWF;

    {
        float4 v0 = *(const float4*)(row + 12 * t);
        float4 v1 = *(const float4*)(row + 12 * t + 4);
        float4 v2 = *(const float4*)(row + 12 * t + 8);
        float4 c0, c1, c2;
        c0.x = v0.x; c0.y = v0.w; c0.z = v1.z; c0.w = v2.y;
        c1.x = v0.y; c1.y = v1.x; c1.z = v1.w; c1.w = v2.z;
        c2.x = v0.z; c2.y = v1.y; c2.z = v2.x; c2.w = v2.w;
        *(float4*)(pl + 0 * PLN + 8 + 4 * t) = c0;
        *(float4*)(pl + 1 * PLN + 8 + 4 * t) = c1;
        *(float4*)(pl + 2 * PLN + 8 + 4 * t) = c2;
    }
    __syncthreads();

    if (t < 48) {                        // mirror halos: 3ch x (8 left + 8 right)
        int c = t >> 4, i = t & 15;
        float* p = pl + c * PLN;
        if (i < 8) { int j = i + 1; p[8 - j] = p[8 + j]; }
        else { int r = i - 8; p[1032 + r] = p[1030 - r]; }
    }
    __syncthreads();

    float g[RAD + 1];
    g[0] = 1.7320508075688773f;
#pragma unroll
    for (int k = 1; k <= RAD; ++k) g[k] = g[k - 1] * (-0.26794919243112270647f);

    float res[3][4];
#pragma unroll
    for (int c = 0; c < 3; ++c) {
        const float* p = pl + c * PLN + 4 * t;   // phys addr of q0-8, aligned
        float w[20];
#pragma unroll
        for (int i = 0; i < 5; ++i) {
            float4 v = *(const float4*)(p + 4 * i);
            w[4 * i] = v.x; w[4 * i + 1] = v.y; w[4 * i + 2] = v.z; w[4 * i + 3] = v.w;
        }
#pragma unroll
        for (int j = 0; j < 4; ++j) {
            float a = g[0] * w[j + 8];
#pragma unroll
            for (int k = 1; k <= 8; ++k)
                a += g[k] * (w[j + 8 - k] + w[j + 8 + k]);
            res[c][j] = a;
        }
    }

    const int b = bp >> 8, h = bp & 255;
    const size_t base = (size_t)b * HW_ + (size_t)h * W_ + 4 * t;
    float4 o01, o2;
    o01.x = pk2(res[0][0], res[1][0]);
    o01.y = pk2(res[0][1], res[1][1]);
    o01.z = pk2(res[0][2], res[1][2]);
    o01.w = pk2(res[0][3], res[1][3]);
    o2.x = res[2][0]; o2.y = res[2][1]; o2.z = res[2][2]; o2.w = res[2][3];
    *(float4*)(p01 + base) = o01;
    *(float4*)(p2 + base) = o2;
}

// ---------------- kernel 2: prefilter along H, in place, f32 math ---------
// blockIdx.y: 0..31 -> plane01 (unpack->f32 FIR->repack), 32..63 -> plane2.
// LDS tile [256 rows][40 dwords]; payload 32 dwords/row.
#define TSTR 40
__global__ __launch_bounds__(256) void k_hfilt(float* __restrict__ p01,
                                               float* __restrict__ p2) {
    __shared__ float tile[H_ * TSTR];   // 40 KiB
    const int t = threadIdx.x;
    const int plane = blockIdx.y;
    const bool is01 = plane < 32;
    const int b = is01 ? plane : plane - 32;
    float* src = (is01 ? p01 : p2) + (size_t)b * HW_ + blockIdx.x * 32;

#pragma unroll
    for (int it = 0; it < 8; ++it) {
        int idx = t + it * 256;          // 0..2047 float4s
        int r = idx >> 3, seg = idx & 7;
        *(float4*)(tile + r * TSTR + seg * 4) =
            *(const float4*)(src + (size_t)r * W_ + seg * 4);
    }
    __syncthreads();

    float g[RAD + 1];
    g[0] = 1.7320508075688773f;
#pragma unroll
    for (int k = 1; k <= RAD; ++k) g[k] = g[k - 1] * (-0.26794919243112270647f);

    const int cg = t & 7;          // dword4 column group
    const int prow = t >> 3;       // 0..31
    const int p0 = prow * 8;

    if (is01) {
        float a0[8][4], a1[8][4];          // c0,c1 f32 accumulators
#pragma unroll
        for (int j = 0; j < 8; ++j)
#pragma unroll
            for (int q = 0; q < 4; ++q) { a0[j][q] = 0.f; a1[j][q] = 0.f; }

#pragma unroll
        for (int r = 0; r < 8 + 2 * RAD; ++r) {    // 24 rows
            int hh = p0 - RAD + r;
            int m1 = hh < 0 ? -hh : hh;
            int m2 = 2 * (H_ - 1) - hh;
            int mp = m1 < m2 ? m1 : m2;
            float4 v = *(const float4*)(tile + mp * TSTR + cg * 4);
            float2 u0 = up2(v.x), u1 = up2(v.y), u2 = up2(v.z), u3 = up2(v.w);
#pragma unroll
            for (int j = 0; j < 8; ++j) {
                const int d = r - RAD - j;
                if (d >= -RAD && d <= RAD) {
                    const float wgt = g[d < 0 ? -d : d];
                    a0[j][0] += wgt * u0.x; a1[j][0] += wgt * u0.y;
                    a0[j][1] += wgt * u1.x; a1[j][1] += wgt * u1.y;
                    a0[j][2] += wgt * u2.x; a1[j][2] += wgt * u2.y;
                    a0[j][3] += wgt * u3.x; a1[j][3] += wgt * u3.y;
                }
            }
        }
#pragma unroll
        for (int j = 0; j < 8; ++j) {
            float4 o;
            o.x = pk2(a0[j][0], a1[j][0]);
            o.y = pk2(a0[j][1], a1[j][1]);
            o.z = pk2(a0[j][2], a1[j][2]);
            o.w = pk2(a0[j][3], a1[j][3]);
            *(float4*)(src + (size_t)(p0 + j) * W_ + cg * 4) = o;
        }
    } else {
        float acc[8][4];
#pragma unroll
        for (int j = 0; j < 8; ++j) {
            acc[j][0] = 0.f; acc[j][1] = 0.f; acc[j][2] = 0.f; acc[j][3] = 0.f;
        }
#pragma unroll
        for (int r = 0; r < 8 + 2 * RAD; ++r) {
            int hh = p0 - RAD + r;
            int m1 = hh < 0 ? -hh : hh;
            int m2 = 2 * (H_ - 1) - hh;
            int mp = m1 < m2 ? m1 : m2;
            float4 v = *(const float4*)(tile + mp * TSTR + cg * 4);
#pragma unroll
            for (int j = 0; j < 8; ++j) {
                const int d = r - RAD - j;
                if (d >= -RAD && d <= RAD) {
                    const float wgt = g[d < 0 ? -d : d];
                    acc[j][0] += wgt * v.x;
                    acc[j][1] += wgt * v.y;
                    acc[j][2] += wgt * v.z;
                    acc[j][3] += wgt * v.w;
                }
            }
        }
#pragma unroll
        for (int j = 0; j < 8; ++j) {
            float4 o;
            o.x = acc[j][0]; o.y = acc[j][1]; o.z = acc[j][2]; o.w = acc[j][3];
            *(float4*)(src + (size_t)(p0 + j) * W_ + cg * 4) = o;
        }
    }
}

// ---------------- kernel 3: 4x4 cubic gather, f32 math --------------------
// grid (1024, 32): thread owns one (b, h, w).
__global__ __launch_bounds__(256) void k_sample(const float* __restrict__ p01,
                                                const float* __restrict__ p2,
                                                const float2* __restrict__ dxy,
                                                float* __restrict__ out) {
    __shared__ float os[768];
    const int t = threadIdx.x;
    const int hw = blockIdx.x * 256 + t;
    const int b = blockIdx.y;
    const int h = hw >> 10, w = hw & 1023;

    float2 d = dxy[hw];
    float cy = (float)h + d.x;
    float cx = (float)w + d.y;
    float byf = floorf(cy), bxf = floorf(cx);
    int by = (int)byf, bx = (int)bxf;
    float wy[4], wx[4];
    cubw(cy - byf, wy);
    cubw(cx - bxf, wx);

    int iyW[4];
#pragma unroll
    for (int r = 0; r < 4; ++r)
        iyW[r] = min(max(by - 1 + r, 0), H_ - 1) * W_;

    const float* cb01 = p01 + (size_t)b * HW_;
    const float* cb2 = p2 + (size_t)b * HW_;
    float s0 = 0.f, s1 = 0.f, s2 = 0.f;

    if (bx >= 1 && bx <= W_ - 3) {
#pragma unroll
        for (int r = 0; r < 4; ++r) {
            int o = iyW[r] + bx - 1;
            f4a v01 = *(const f4a*)(cb01 + o);
            f4a v2 = *(const f4a*)(cb2 + o);
            float2 u0 = up2(v01.x), u1 = up2(v01.y), u2 = up2(v01.z), u3 = up2(v01.w);
            float wyr = wy[r];
            s0 += wyr * (wx[0] * u0.x + wx[1] * u1.x + wx[2] * u2.x + wx[3] * u3.x);
            s1 += wyr * (wx[0] * u0.y + wx[1] * u1.y + wx[2] * u2.y + wx[3] * u3.y);
            s2 += wyr * (wx[0] * v2.x + wx[1] * v2.y + wx[2] * v2.z + wx[3] * v2.w);
        }
    } else {
        int ix4[4];
#pragma unroll
        for (int k = 0; k < 4; ++k) ix4[k] = min(max(bx - 1 + k, 0), W_ - 1);
#pragma unroll
        for (int r = 0; r < 4; ++r) {
            float wyr = wy[r];
#pragma unroll
            for (int k = 0; k < 4; ++k) {
                float wk = wyr * wx[k];
                int o = iyW[r] + ix4[k];
                float2 u = up2(cb01[o]);
                s0 += wk * u.x;
                s1 += wk * u.y;
                s2 += wk * cb2[o];
            }
        }
    }

    os[3 * t + 0] = clamp01(s0);
    os[3 * t + 1] = clamp01(s1);
    os[3 * t + 2] = clamp01(s2);
    __syncthreads();

    if (t < 192) {
        float4 v = *(const float4*)(os + 4 * t);
        *(float4*)(out + ((size_t)b * HW_ + (size_t)blockIdx.x * 256) * 3 + 4 * t) = v;
    }
}

extern "C" void kernel_launch(void* const* d_in, const int* in_sizes, int n_in,
                              void* d_out, int out_size, void* d_ws, size_t ws_size,
                              hipStream_t stream) {
    const float* x = (const float*)d_in[0];      // [32,256,1024,3]
    const float* disp = (const float*)d_in[1];   // [2,3,3]
    float* out = (float*)d_out;

    char* ws = (char*)d_ws;
    float* p01 = (float*)ws;                       // 32 MiB (half2 per pixel)
    float* p2 = (float*)(ws + 33554432ull);        // 32 MiB (f32 c2)
    float2* dxy = (float2*)(ws + 67108864ull);     // 2 MiB

    k_disp<<<dim3((H_ * W_) / 256), dim3(256), 0, stream>>>(disp, dxy);

    k_wfilt<<<dim3(B_ * H_), dim3(256), 0, stream>>>(x, p01, p2);

    k_hfilt<<<dim3(W_ / 32, 2 * B_), dim3(256), 0, stream>>>(p01, p2);

    k_sample<<<dim3((H_ * W_) / 256, B_), dim3(256), 0, stream>>>(p01, p2, dxy, out);
}